// Round 3
// baseline (3216.025 us; speedup 1.0000x reference)
//
#include <hip/hip_runtime.h>
#include <hip/hip_bf16.h>

// ---------------------------------------------------------------------------
// GIN forward (all I/O fp32):
//   2x GINConv(128->128->128, eps=0) + ReLU, L2 row-normalize,
//   per-node MLP 128->32->32->32, per-graph Gram (32x32 -> 1024),
//   per-graph MLP 1024->32->32->2.
// Internals: node features bf16 (gather traffic / MFMA), fp32 accumulate.
// Aggregation: bucket-binned edge list (1024 buckets x 128 nodes) +
// per-bucket LDS fp32 accumulator (ds_add_f32) — no per-node CSR.
// ---------------------------------------------------------------------------

#define NN 131072      // nodes
#define NE 2097152     // edges
#define NG 512         // graphs
#define NB 1024        // buckets (128 nodes each)
#define BCH 16384      // edges per binning block (NE/128)

typedef unsigned short u16;
typedef unsigned int u32;
typedef __attribute__((ext_vector_type(8))) short short8;   // 8 x bf16
typedef __attribute__((ext_vector_type(4))) float f32x4;

__device__ __forceinline__ float bf2f(u16 u) {
    union { u32 i; float f; } x; x.i = ((u32)u) << 16; return x.f;
}
__device__ __forceinline__ u16 f2bf(float f) {
    union { u32 i; float f; } x; x.f = f;
    u32 r = x.i + 0x7fffu + ((x.i >> 16) & 1u);   // RNE
    return (u16)(r >> 16);
}

// ---------------- cast x: fp32 -> bf16 ----------------
__global__ __launch_bounds__(256) void cast_x(const float* __restrict__ xf,
                                              u16* __restrict__ xb) {
    int i = blockIdx.x * 256 + threadIdx.x;       // 8 floats per thread
    const float4* src = (const float4*)xf;
    float4 a = src[2 * i], b = src[2 * i + 1];
    uint4 o;
    o.x = (u32)f2bf(a.x) | ((u32)f2bf(a.y) << 16);
    o.y = (u32)f2bf(a.z) | ((u32)f2bf(a.w) << 16);
    o.z = (u32)f2bf(b.x) | ((u32)f2bf(b.y) << 16);
    o.w = (u32)f2bf(b.z) | ((u32)f2bf(b.w) << 16);
    ((uint4*)xb)[i] = o;
}

// ---------------- edge binning: count per bucket ----------------
__global__ __launch_bounds__(256) void bin_count(const int* __restrict__ gdst,
                                                 int* __restrict__ bcnt) {
    __shared__ int bc[NB];
    int t = threadIdx.x;
    for (int i = 0; i < 4; ++i) bc[t + i * 256] = 0;
    __syncthreads();
    int base = blockIdx.x * BCH;
    for (int i = 0; i < BCH / 256; ++i) {
        int d = gdst[base + i * 256 + t];
        atomicAdd(&bc[d >> 7], 1);
    }
    __syncthreads();
    for (int i = 0; i < 4; ++i) {
        int b = t + i * 256;
        if (bc[b]) atomicAdd(&bcnt[b], bc[b]);
    }
}

// ---------------- scan over 1024 buckets ----------------
__global__ __launch_bounds__(1024) void scan_buckets(const int* __restrict__ bcnt,
                                                     int* __restrict__ bbase,
                                                     int* __restrict__ cursor) {
    __shared__ int tmp[NB];
    int t = threadIdx.x;
    tmp[t] = bcnt[t];
    __syncthreads();
    for (int o = 1; o < NB; o <<= 1) {
        int u = (t >= o) ? tmp[t - o] : 0;
        __syncthreads();
        tmp[t] += u;
        __syncthreads();
    }
    int ex = tmp[t] - bcnt[t];
    bbase[t] = ex;
    cursor[t] = ex;
    if (t == NB - 1) bbase[NB] = tmp[t];
}

// ---------------- scatter edges into bucket-grouped array ----------------
// ebuf[e] = (src << 7) | (dst & 127), grouped by bucket = dst >> 7
__global__ __launch_bounds__(256) void bin_scatter(const int* __restrict__ gsrc,
                                                   const int* __restrict__ gdst,
                                                   int* __restrict__ cursor,
                                                   u32* __restrict__ ebuf) {
    __shared__ int lc[NB];   // local counts
    __shared__ int rb[NB];   // reserved run base (global)
    __shared__ int lb[NB];   // local bump
    int t = threadIdx.x;
    for (int i = 0; i < 4; ++i) lc[t + i * 256] = 0;
    __syncthreads();
    int base = blockIdx.x * BCH;
    for (int i = 0; i < BCH / 256; ++i) {
        int d = gdst[base + i * 256 + t];
        atomicAdd(&lc[d >> 7], 1);
    }
    __syncthreads();
    for (int i = 0; i < 4; ++i) {
        int b = t + i * 256;
        int c = lc[b];
        rb[b] = c ? atomicAdd(&cursor[b], c) : 0;
        lb[b] = 0;
    }
    __syncthreads();
    for (int i = 0; i < BCH / 256; ++i) {
        int idx = base + i * 256 + t;
        int d = gdst[idx];
        int s = gsrc[idx];
        int b = d >> 7;
        int o = atomicAdd(&lb[b], 1);
        ebuf[rb[b] + o] = ((u32)s << 7) | (u32)(d & 127);
    }
}

// ---------------- aggregation: T[i] = X[i] + sum_{j->i} X[j] ----------------
// Block = one bucket of 128 nodes. fp32 accumulator in LDS (64KB).
// LDS layout per node row (128 floats): position p<64 holds feat 2p,
// position 64+p holds feat 2p+1  -> lane l touches banks l%32 only (2-way, free).
__global__ __launch_bounds__(256) void aggregate_lds(const u16* __restrict__ X,
                                                     const u32* __restrict__ ebuf,
                                                     const int* __restrict__ bbase,
                                                     u16* __restrict__ T) {
    __shared__ float acc[128 * 128];
    int t = threadIdx.x, lane = t & 63, wave = t >> 6;
    int bkt = blockIdx.x;
    const u32* Xu = (const u32*)X;

    // init acc with the node's own row (eps=0 self term)
    for (int r = wave; r < 128; r += 4) {
        u32 v = Xu[(size_t)(bkt * 128 + r) * 64 + lane];
        acc[r * 128 + lane]      = bf2f((u16)v);
        acc[r * 128 + 64 + lane] = bf2f((u16)(v >> 16));
    }
    __syncthreads();

    int e0 = bbase[bkt], e1 = bbase[bkt + 1];
    // waves take 64-edge batches round-robin; 8-deep gather pipeline
    for (int base = e0 + wave * 64; base < e1; base += 256) {
        int n = min(64, e1 - base);
        u32 pk = (base + lane < e1) ? ebuf[base + lane] : 0;
        if (n == 64) {
#pragma unroll
            for (int jj = 0; jj < 64; jj += 8) {
                u32 w[8]; int loc[8];
#pragma unroll
                for (int d = 0; d < 8; ++d) {
                    u32 p = __shfl(pk, jj + d, 64);
                    loc[d] = (int)(p & 127);
                    w[d] = Xu[(size_t)(p >> 7) * 64 + lane];
                }
#pragma unroll
                for (int d = 0; d < 8; ++d) {
                    atomicAdd(&acc[loc[d] * 128 + lane],      bf2f((u16)w[d]));
                    atomicAdd(&acc[loc[d] * 128 + 64 + lane], bf2f((u16)(w[d] >> 16)));
                }
            }
        } else {
            for (int j = 0; j < n; ++j) {
                u32 p = __shfl(pk, j, 64);
                int loc = (int)(p & 127);
                u32 w = Xu[(size_t)(p >> 7) * 64 + lane];
                atomicAdd(&acc[loc * 128 + lane],      bf2f((u16)w));
                atomicAdd(&acc[loc * 128 + 64 + lane], bf2f((u16)(w >> 16)));
            }
        }
    }
    __syncthreads();

    // write out as bf16 pairs (standard feature order restored by the perm)
    u32* Tu = (u32*)T;
    for (int r = wave; r < 128; r += 4) {
        float lo = acc[r * 128 + lane];
        float hi = acc[r * 128 + 64 + lane];
        Tu[(size_t)(bkt * 128 + r) * 64 + lane] = (u32)f2bf(lo) | ((u32)f2bf(hi) << 16);
    }
}

// ---------------- weight transpose + cast: Wt[n][k] = (bf16)W[k][n] ----------------
__global__ __launch_bounds__(256) void transpose_w(const float* a, const float* b,
                                                   const float* c, const float* d, u16* Wt) {
    const float* w = (blockIdx.x == 0) ? a : (blockIdx.x == 1) ? b : (blockIdx.x == 2) ? c : d;
    u16* o = Wt + blockIdx.x * 16384;
    for (int i = 0; i < 64; ++i) {
        int idx = threadIdx.x + i * 256;
        o[(idx & 127) * 128 + (idx >> 7)] = f2bf(w[idx]);
    }
}

// ---------------- GEMM: C = relu(A @ W + b) via MFMA bf16 ----------------
__global__ __launch_bounds__(256) void gemm_relu(const u16* __restrict__ A,
                                                 const u16* __restrict__ Wt,
                                                 const float* __restrict__ bias,
                                                 u16* __restrict__ C) {
    __shared__ u16 As[64][136];
    __shared__ u16 Ws[128][136];
    int tid = threadIdx.x;
    size_t rowBase = (size_t)blockIdx.x * 64;

    for (int i = 0; i < 4; ++i) {
        int c = tid + i * 256;
        int r = c >> 4, co = (c & 15) << 3;
        uint4 v = *(const uint4*)(A + (rowBase + r) * 128 + co);
        *(uint4*)&As[r][co] = v;
    }
    for (int i = 0; i < 8; ++i) {
        int c = tid + i * 256;
        int r = c >> 4, co = (c & 15) << 3;
        uint4 v = *(const uint4*)(Wt + r * 128 + co);
        *(uint4*)&Ws[r][co] = v;
    }
    __syncthreads();

    int lane = tid & 63, wave = tid >> 6;
    int quad = lane >> 4, l16 = lane & 15;

    f32x4 acc[8];
#pragma unroll
    for (int t = 0; t < 8; ++t) acc[t] = (f32x4){0.f, 0.f, 0.f, 0.f};

#pragma unroll
    for (int c = 0; c < 4; ++c) {
        short8 a = *(const short8*)&As[wave * 16 + l16][c * 32 + quad * 8];
#pragma unroll
        for (int t = 0; t < 8; ++t) {
            short8 b = *(const short8*)&Ws[t * 16 + l16][c * 32 + quad * 8];
            acc[t] = __builtin_amdgcn_mfma_f32_16x16x32_bf16(a, b, acc[t], 0, 0, 0);
        }
    }

#pragma unroll
    for (int t = 0; t < 8; ++t) {
        int col = t * 16 + l16;
        float bv = bias[col];
#pragma unroll
        for (int r = 0; r < 4; ++r) {
            int row = wave * 16 + quad * 4 + r;
            float v = fmaxf(acc[t][r] + bv, 0.f);
            C[(rowBase + row) * 128 + col] = f2bf(v);
        }
    }
}

// ---------------- normalize + per-node MLP (128->32->32->32), fp32 weights ----------------
__global__ __launch_bounds__(256) void norm_mlp(const u16* __restrict__ X,
                                                const float* Ws1, const float* bs1,
                                                const float* Ws2, const float* bs2,
                                                const float* Ws3, const float* bs3,
                                                float* __restrict__ S) {
    __shared__ float W1s[128 * 32];
    __shared__ float W2s[32 * 32];
    __shared__ float W3s[32 * 32];
    __shared__ float b1s[32], b2s[32], b3s[32];
    __shared__ float hbuf[4][128];
    __shared__ float sbuf[4][32];
    int t = threadIdx.x;
    for (int i = 0; i < 16; ++i) W1s[t + i * 256] = Ws1[t + i * 256];
    for (int i = 0; i < 4; ++i) { W2s[t + i * 256] = Ws2[t + i * 256]; W3s[t + i * 256] = Ws3[t + i * 256]; }
    if (t < 32) { b1s[t] = bs1[t]; b2s[t] = bs2[t]; b3s[t] = bs3[t]; }
    __syncthreads();

    int wave = t >> 6, lane = t & 63;
    int node = blockIdx.x * 4 + wave;
    u32 v = ((const u32*)X)[(size_t)node * 64 + lane];
    float f0 = bf2f((u16)v), f1 = bf2f((u16)(v >> 16));
    float ss = f0 * f0 + f1 * f1;
    for (int o = 1; o < 64; o <<= 1) ss += __shfl_xor(ss, o, 64);
    float inv = 1.0f / fmaxf(sqrtf(ss), 1e-12f);
    hbuf[wave][2 * lane] = f0 * inv;
    hbuf[wave][2 * lane + 1] = f1 * inv;
    __syncthreads();

    int j = lane & 31, half = lane >> 5;
    float p = 0.f;
    for (int i = 0; i < 64; ++i) { int k = half * 64 + i; p += hbuf[wave][k] * W1s[k * 32 + j]; }
    p += __shfl_xor(p, 32, 64);
    float s1 = fmaxf(p + b1s[j], 0.f);
    if (!half) sbuf[wave][j] = s1;
    __syncthreads();

    p = 0.f;
    for (int i = 0; i < 16; ++i) { int k = half * 16 + i; p += sbuf[wave][k] * W2s[k * 32 + j]; }
    p += __shfl_xor(p, 32, 64);
    float s2 = fmaxf(p + b2s[j], 0.f);
    __syncthreads();
    if (!half) sbuf[wave][j] = s2;
    __syncthreads();

    p = 0.f;
    for (int i = 0; i < 16; ++i) { int k = half * 16 + i; p += sbuf[wave][k] * W3s[k * 32 + j]; }
    p += __shfl_xor(p, 32, 64);
    float s3 = fmaxf(p + b3s[j], 0.f);
    if (!half) S[(size_t)node * 32 + j] = s3;
}

// ---------------- per-graph Gram: out[g][f][e] = sum_n S[g,n,f]*S[g,n,e] ----------------
__global__ __launch_bounds__(256) void gram(const float* __restrict__ S,
                                            float* __restrict__ out) {
    __shared__ float Sg[256 * 32];
    int t = threadIdx.x, g = blockIdx.x;
    const float4* src = (const float4*)(S + (size_t)g * 8192);
    float4* dst = (float4*)Sg;
    for (int i = 0; i < 8; ++i) dst[t + i * 256] = src[t + i * 256];
    __syncthreads();

    int f = t >> 3, e0 = (t & 7) << 2;
    float4 a = {0.f, 0.f, 0.f, 0.f};
    for (int n = 0; n < 256; ++n) {
        float sf = Sg[n * 32 + f];
        float4 se = *(const float4*)&Sg[n * 32 + e0];
        a.x += sf * se.x; a.y += sf * se.y; a.z += sf * se.z; a.w += sf * se.w;
    }
    *(float4*)(out + (size_t)g * 1024 + f * 32 + e0) = a;
}

// ---------------- per-graph MLP: 1024->32->32->2 (fp32) ----------------
__global__ __launch_bounds__(256) void graph_mlp(const float* __restrict__ HH,
                                                 const float* Wm1, const float* bm1,
                                                 const float* Wm2, const float* bm2,
                                                 const float* Wm3, const float* bm3,
                                                 float* __restrict__ out) {
    __shared__ float hh[1024];
    __shared__ float red[256];
    __shared__ float o1[32];
    __shared__ float o2[32];
    int t = threadIdx.x, g = blockIdx.x;
    ((float4*)hh)[t] = ((const float4*)(HH + (size_t)g * 1024))[t];
    __syncthreads();

    int j = t & 31, part = t >> 5;
    float p = 0.f;
    for (int i = 0; i < 128; ++i) { int k = part * 128 + i; p += hh[k] * Wm1[k * 32 + j]; }
    red[t] = p;
    __syncthreads();
    if (t < 32) {
        float s = 0.f;
        for (int q = 0; q < 8; ++q) s += red[q * 32 + t];
        o1[t] = fmaxf(s + bm1[t], 0.f);
    }
    __syncthreads();
    if (t < 32) {
        float s = 0.f;
        for (int k = 0; k < 32; ++k) s += o1[k] * Wm2[k * 32 + t];
        o2[t] = fmaxf(s + bm2[t], 0.f);
    }
    __syncthreads();
    if (t < 2) {
        float s = 0.f;
        for (int k = 0; k < 32; ++k) s += o2[k] * Wm3[k * 2 + t];
        out[524288 + g * 2 + t] = fmaxf(s + bm3[t], 0.f);
    }
}

// ---------------------------------------------------------------------------
extern "C" void kernel_launch(void* const* d_in, const int* in_sizes, int n_in,
                              void* d_out, int out_size, void* d_ws, size_t ws_size,
                              hipStream_t stream) {
    const float* x   = (const float*)d_in[0];
    const int*   ei  = (const int*)d_in[1];
    const float* W1a = (const float*)d_in[2];  const float* b1a = (const float*)d_in[3];
    const float* W2a = (const float*)d_in[4];  const float* b2a = (const float*)d_in[5];
    const float* W1b = (const float*)d_in[6];  const float* b1b = (const float*)d_in[7];
    const float* W2b = (const float*)d_in[8];  const float* b2b = (const float*)d_in[9];
    const float* Ws1 = (const float*)d_in[10]; const float* bs1 = (const float*)d_in[11];
    const float* Ws2 = (const float*)d_in[12]; const float* bs2 = (const float*)d_in[13];
    const float* Ws3 = (const float*)d_in[14]; const float* bs3 = (const float*)d_in[15];
    const float* Wm1 = (const float*)d_in[16]; const float* bm1 = (const float*)d_in[17];
    const float* Wm2 = (const float*)d_in[18]; const float* bm2 = (const float*)d_in[19];
    const float* Wm3 = (const float*)d_in[20]; const float* bm3 = (const float*)d_in[21];
    float* out = (float*)d_out;

    const int* gsrc = ei;
    const int* gdst = ei + NE;

    char* ws = (char*)d_ws;
    size_t off = 0;
    auto alloc = [&](size_t bytes) { size_t r = off; off = (off + bytes + 255) & ~(size_t)255; return r; };
    int*  bcnt   = (int*)(ws + alloc((size_t)NB * 4));
    int*  bbase  = (int*)(ws + alloc((size_t)(NB + 1) * 4));
    int*  cursor = (int*)(ws + alloc((size_t)NB * 4));
    u32*  ebuf   = (u32*)(ws + alloc((size_t)NE * 4));
    u16*  Wt     = (u16*)(ws + alloc(4 * 16384 * 2));
    u16*  X0     = (u16*)(ws + alloc((size_t)NN * 128 * 2));   // xb / hA / hB
    u16*  B1     = (u16*)(ws + alloc((size_t)NN * 128 * 2));
    u16*  B2     = (u16*)(ws + alloc((size_t)NN * 128 * 2));
    float* S     = (float*)B1;                                  // alias: B1 dead after last gemm
    (void)ws_size; (void)n_in; (void)in_sizes; (void)out_size;

    // ---- edge binning (replaces per-node CSR) ----
    hipMemsetAsync(bcnt, 0, (size_t)NB * 4, stream);
    bin_count<<<NE / BCH, 256, 0, stream>>>(gdst, bcnt);
    scan_buckets<<<1, 1024, 0, stream>>>(bcnt, bbase, cursor);
    bin_scatter<<<NE / BCH, 256, 0, stream>>>(gsrc, gdst, cursor, ebuf);

    // ---- casts ----
    cast_x<<<NN * 128 / (256 * 8), 256, 0, stream>>>(x, X0);
    transpose_w<<<4, 256, 0, stream>>>(W1a, W2a, W1b, W2b, Wt);

    // ---- layer A ----
    aggregate_lds<<<NB, 256, 0, stream>>>(X0, ebuf, bbase, B1);
    gemm_relu<<<NN / 64, 256, 0, stream>>>(B1, Wt + 0 * 16384, b1a, B2);
    gemm_relu<<<NN / 64, 256, 0, stream>>>(B2, Wt + 1 * 16384, b2a, X0);   // hA
    // ---- layer B ----
    aggregate_lds<<<NB, 256, 0, stream>>>(X0, ebuf, bbase, B1);
    gemm_relu<<<NN / 64, 256, 0, stream>>>(B1, Wt + 2 * 16384, b1b, B2);
    gemm_relu<<<NN / 64, 256, 0, stream>>>(B2, Wt + 3 * 16384, b2b, X0);   // hB

    // ---- normalize + per-node MLP (S aliases B1) ----
    norm_mlp<<<NN / 4, 256, 0, stream>>>(X0, Ws1, bs1, Ws2, bs2, Ws3, bs3, S);
    // ---- per-graph Gram -> out[0:524288], then graph MLP -> out[524288:] ----
    gram<<<NG, 256, 0, stream>>>(S, out);
    graph_mlp<<<NG, 256, 0, stream>>>(out, Wm1, bm1, Wm2, bm2, Wm3, bm3, out);
}

// Round 4
// 666.397 us; speedup vs baseline: 4.8260x; 4.8260x over previous
//
#include <hip/hip_runtime.h>
#include <hip/hip_bf16.h>

// ---------------------------------------------------------------------------
// GIN forward (all I/O fp32):
//   2x GINConv(128->128->128, eps=0) + ReLU, L2 row-normalize,
//   per-node MLP 128->32->32->32, per-graph Gram (32x32 -> 1024),
//   per-graph MLP 1024->32->32->2.
// Internals: node features bf16 (gather traffic / MFMA), fp32 accumulate.
// Aggregation: bucket-binned edges (1024 buckets x 128 nodes) -> per-bucket
// LDS counting sort -> register-accumulator gather. NO float atomics anywhere.
// ---------------------------------------------------------------------------

#define NN 131072      // nodes
#define NE 2097152     // edges
#define NG 512         // graphs
#define NB 1024        // buckets (128 nodes each)
#define BCH 16384      // edges per binning block (NE/128)
#define CAP 3072       // edge-sort chunk capacity (bucket avg 2048, sigma ~45)

typedef unsigned short u16;
typedef unsigned int u32;
typedef __attribute__((ext_vector_type(8))) short short8;   // 8 x bf16
typedef __attribute__((ext_vector_type(4))) float f32x4;

__device__ __forceinline__ float bf2f(u16 u) {
    union { u32 i; float f; } x; x.i = ((u32)u) << 16; return x.f;
}
__device__ __forceinline__ u16 f2bf(float f) {
    union { u32 i; float f; } x; x.f = f;
    u32 r = x.i + 0x7fffu + ((x.i >> 16) & 1u);   // RNE
    return (u16)(r >> 16);
}

// ---------------- cast x: fp32 -> bf16 ----------------
__global__ __launch_bounds__(256) void cast_x(const float* __restrict__ xf,
                                              u16* __restrict__ xb) {
    int i = blockIdx.x * 256 + threadIdx.x;       // 8 floats per thread
    const float4* src = (const float4*)xf;
    float4 a = src[2 * i], b = src[2 * i + 1];
    uint4 o;
    o.x = (u32)f2bf(a.x) | ((u32)f2bf(a.y) << 16);
    o.y = (u32)f2bf(a.z) | ((u32)f2bf(a.w) << 16);
    o.z = (u32)f2bf(b.x) | ((u32)f2bf(b.y) << 16);
    o.w = (u32)f2bf(b.z) | ((u32)f2bf(b.w) << 16);
    ((uint4*)xb)[i] = o;
}

// ---------------- edge binning: count per bucket ----------------
__global__ __launch_bounds__(256) void bin_count(const int* __restrict__ gdst,
                                                 int* __restrict__ bcnt) {
    __shared__ int bc[NB];
    int t = threadIdx.x;
    for (int i = 0; i < 4; ++i) bc[t + i * 256] = 0;
    __syncthreads();
    int base = blockIdx.x * BCH;
    for (int i = 0; i < BCH / 256; ++i) {
        int d = gdst[base + i * 256 + t];
        atomicAdd(&bc[d >> 7], 1);
    }
    __syncthreads();
    for (int i = 0; i < 4; ++i) {
        int b = t + i * 256;
        if (bc[b]) atomicAdd(&bcnt[b], bc[b]);
    }
}

// ---------------- scan over 1024 buckets ----------------
__global__ __launch_bounds__(1024) void scan_buckets(const int* __restrict__ bcnt,
                                                     int* __restrict__ bbase,
                                                     int* __restrict__ cursor) {
    __shared__ int tmp[NB];
    int t = threadIdx.x;
    tmp[t] = bcnt[t];
    __syncthreads();
    for (int o = 1; o < NB; o <<= 1) {
        int u = (t >= o) ? tmp[t - o] : 0;
        __syncthreads();
        tmp[t] += u;
        __syncthreads();
    }
    int ex = tmp[t] - bcnt[t];
    bbase[t] = ex;
    cursor[t] = ex;
    if (t == NB - 1) bbase[NB] = tmp[t];
}

// ---------------- scatter edges into bucket-grouped array ----------------
// ebuf[e] = (src << 7) | (dst & 127), grouped by bucket = dst >> 7
__global__ __launch_bounds__(256) void bin_scatter(const int* __restrict__ gsrc,
                                                   const int* __restrict__ gdst,
                                                   int* __restrict__ cursor,
                                                   u32* __restrict__ ebuf) {
    __shared__ int lc[NB];   // local counts
    __shared__ int rb[NB];   // reserved run base (global)
    __shared__ int lb[NB];   // local bump
    int t = threadIdx.x;
    for (int i = 0; i < 4; ++i) lc[t + i * 256] = 0;
    __syncthreads();
    int base = blockIdx.x * BCH;
    for (int i = 0; i < BCH / 256; ++i) {
        int d = gdst[base + i * 256 + t];
        atomicAdd(&lc[d >> 7], 1);
    }
    __syncthreads();
    for (int i = 0; i < 4; ++i) {
        int b = t + i * 256;
        int c = lc[b];
        rb[b] = c ? atomicAdd(&cursor[b], c) : 0;
        lb[b] = 0;
    }
    __syncthreads();
    for (int i = 0; i < BCH / 256; ++i) {
        int idx = base + i * 256 + t;
        int d = gdst[idx];
        int s = gsrc[idx];
        int b = d >> 7;
        int o = atomicAdd(&lb[b], 1);
        ebuf[rb[b] + o] = ((u32)s << 7) | (u32)(d & 127);
    }
}

// ---------------- aggregation: T[i] = X[i] + sum_{j->i} X[j] ----------------
// Block = one bucket (128 nodes), 8 waves. Per chunk: LDS counting sort of
// edges by local dst (int atomics only), then each wave gathers for its 16
// nodes with fp32 accumulators in REGISTERS, 4-deep load pipeline.
__global__ __launch_bounds__(512) void aggregate_bucket(const u16* __restrict__ X,
                                                        const u32* __restrict__ ebuf,
                                                        const int* __restrict__ bbase,
                                                        u16* __restrict__ T) {
    __shared__ int lcnt[128];
    __shared__ int lstart[128];
    __shared__ int lofs[128];
    __shared__ int sorted[CAP];
    int t = threadIdx.x, lane = t & 63, wave = t >> 6;   // 8 waves
    int bkt = blockIdx.x;
    const u32* Xu = (const u32*)X;

    // init register accumulators with own row (eps=0 self term)
    float a0[16], a1[16];
#pragma unroll
    for (int i = 0; i < 16; ++i) {
        int row = bkt * 128 + wave * 16 + i;
        u32 v = Xu[(size_t)row * 64 + lane];
        a0[i] = bf2f((u16)v);
        a1[i] = bf2f((u16)(v >> 16));
    }

    int e0 = bbase[bkt], e1 = bbase[bkt + 1];
    for (int cs = e0; cs < e1; cs += CAP) {
        int n = min(CAP, e1 - cs);
        if (t < 128) lcnt[t] = 0;
        __syncthreads();
        for (int j = t; j < n; j += 512)
            atomicAdd(&lcnt[ebuf[cs + j] & 127], 1);
        __syncthreads();
        if (wave == 0) {                         // exclusive scan of 128 counts
            int c0 = lcnt[2 * lane], c1 = lcnt[2 * lane + 1];
            int s = c0 + c1, e = s;
            for (int o = 1; o < 64; o <<= 1) {
                int u = __shfl_up(e, o, 64);
                if (lane >= o) e += u;
            }
            int excl = e - s;
            lstart[2 * lane] = excl;      lofs[2 * lane] = excl;
            lstart[2 * lane + 1] = excl + c0; lofs[2 * lane + 1] = excl + c0;
        }
        __syncthreads();
        for (int j = t; j < n; j += 512) {       // place: node-sorted src list
            u32 e = ebuf[cs + j];
            int pos = atomicAdd(&lofs[e & 127], 1);
            sorted[pos] = (int)(e >> 7);
        }
        __syncthreads();
        // gather + accumulate (no atomics; sorted[] reads are wave-broadcast)
#pragma unroll
        for (int i = 0; i < 16; ++i) {
            int node = wave * 16 + i;
            int p = lstart[node], pe = p + lcnt[node];
            for (; p + 4 <= pe; p += 4) {
                int s0 = sorted[p], s1 = sorted[p + 1];
                int s2 = sorted[p + 2], s3 = sorted[p + 3];
                u32 w0 = Xu[(size_t)s0 * 64 + lane];
                u32 w1 = Xu[(size_t)s1 * 64 + lane];
                u32 w2 = Xu[(size_t)s2 * 64 + lane];
                u32 w3 = Xu[(size_t)s3 * 64 + lane];
                a0[i] += bf2f((u16)w0) + bf2f((u16)w1) + bf2f((u16)w2) + bf2f((u16)w3);
                a1[i] += bf2f((u16)(w0 >> 16)) + bf2f((u16)(w1 >> 16)) +
                         bf2f((u16)(w2 >> 16)) + bf2f((u16)(w3 >> 16));
            }
            for (; p < pe; ++p) {
                u32 w = Xu[(size_t)sorted[p] * 64 + lane];
                a0[i] += bf2f((u16)w);
                a1[i] += bf2f((u16)(w >> 16));
            }
        }
        __syncthreads();                         // protect lcnt/sorted for next chunk
    }

    u32* Tu = (u32*)T;
#pragma unroll
    for (int i = 0; i < 16; ++i) {
        int row = bkt * 128 + wave * 16 + i;
        Tu[(size_t)row * 64 + lane] = (u32)f2bf(a0[i]) | ((u32)f2bf(a1[i]) << 16);
    }
}

// ---------------- weight transpose + cast: Wt[n][k] = (bf16)W[k][n] ----------------
__global__ __launch_bounds__(256) void transpose_w(const float* a, const float* b,
                                                   const float* c, const float* d, u16* Wt) {
    const float* w = (blockIdx.x == 0) ? a : (blockIdx.x == 1) ? b : (blockIdx.x == 2) ? c : d;
    u16* o = Wt + blockIdx.x * 16384;
    for (int i = 0; i < 64; ++i) {
        int idx = threadIdx.x + i * 256;
        o[(idx & 127) * 128 + (idx >> 7)] = f2bf(w[idx]);
    }
}

// ---------------- GEMM: C = relu(A @ W + b) via MFMA bf16 ----------------
__global__ __launch_bounds__(256) void gemm_relu(const u16* __restrict__ A,
                                                 const u16* __restrict__ Wt,
                                                 const float* __restrict__ bias,
                                                 u16* __restrict__ C) {
    __shared__ u16 As[64][136];
    __shared__ u16 Ws[128][136];
    int tid = threadIdx.x;
    size_t rowBase = (size_t)blockIdx.x * 64;

    for (int i = 0; i < 4; ++i) {
        int c = tid + i * 256;
        int r = c >> 4, co = (c & 15) << 3;
        uint4 v = *(const uint4*)(A + (rowBase + r) * 128 + co);
        *(uint4*)&As[r][co] = v;
    }
    for (int i = 0; i < 8; ++i) {
        int c = tid + i * 256;
        int r = c >> 4, co = (c & 15) << 3;
        uint4 v = *(const uint4*)(Wt + r * 128 + co);
        *(uint4*)&Ws[r][co] = v;
    }
    __syncthreads();

    int lane = tid & 63, wave = tid >> 6;
    int quad = lane >> 4, l16 = lane & 15;

    f32x4 acc[8];
#pragma unroll
    for (int t = 0; t < 8; ++t) acc[t] = (f32x4){0.f, 0.f, 0.f, 0.f};

#pragma unroll
    for (int c = 0; c < 4; ++c) {
        short8 a = *(const short8*)&As[wave * 16 + l16][c * 32 + quad * 8];
#pragma unroll
        for (int t = 0; t < 8; ++t) {
            short8 b = *(const short8*)&Ws[t * 16 + l16][c * 32 + quad * 8];
            acc[t] = __builtin_amdgcn_mfma_f32_16x16x32_bf16(a, b, acc[t], 0, 0, 0);
        }
    }

#pragma unroll
    for (int t = 0; t < 8; ++t) {
        int col = t * 16 + l16;
        float bv = bias[col];
#pragma unroll
        for (int r = 0; r < 4; ++r) {
            int row = wave * 16 + quad * 4 + r;
            float v = fmaxf(acc[t][r] + bv, 0.f);
            C[(rowBase + row) * 128 + col] = f2bf(v);
        }
    }
}

// ---------------- normalize + per-node MLP (128->32->32->32), fp32 weights ----------------
__global__ __launch_bounds__(256) void norm_mlp(const u16* __restrict__ X,
                                                const float* Ws1, const float* bs1,
                                                const float* Ws2, const float* bs2,
                                                const float* Ws3, const float* bs3,
                                                float* __restrict__ S) {
    __shared__ float W1s[128 * 32];
    __shared__ float W2s[32 * 32];
    __shared__ float W3s[32 * 32];
    __shared__ float b1s[32], b2s[32], b3s[32];
    __shared__ float hbuf[4][128];
    __shared__ float sbuf[4][32];
    int t = threadIdx.x;
    for (int i = 0; i < 16; ++i) W1s[t + i * 256] = Ws1[t + i * 256];
    for (int i = 0; i < 4; ++i) { W2s[t + i * 256] = Ws2[t + i * 256]; W3s[t + i * 256] = Ws3[t + i * 256]; }
    if (t < 32) { b1s[t] = bs1[t]; b2s[t] = bs2[t]; b3s[t] = bs3[t]; }
    __syncthreads();

    int wave = t >> 6, lane = t & 63;
    int node = blockIdx.x * 4 + wave;
    u32 v = ((const u32*)X)[(size_t)node * 64 + lane];
    float f0 = bf2f((u16)v), f1 = bf2f((u16)(v >> 16));
    float ss = f0 * f0 + f1 * f1;
    for (int o = 1; o < 64; o <<= 1) ss += __shfl_xor(ss, o, 64);
    float inv = 1.0f / fmaxf(sqrtf(ss), 1e-12f);
    hbuf[wave][2 * lane] = f0 * inv;
    hbuf[wave][2 * lane + 1] = f1 * inv;
    __syncthreads();

    int j = lane & 31, half = lane >> 5;
    float p = 0.f;
    for (int i = 0; i < 64; ++i) { int k = half * 64 + i; p += hbuf[wave][k] * W1s[k * 32 + j]; }
    p += __shfl_xor(p, 32, 64);
    float s1 = fmaxf(p + b1s[j], 0.f);
    if (!half) sbuf[wave][j] = s1;
    __syncthreads();

    p = 0.f;
    for (int i = 0; i < 16; ++i) { int k = half * 16 + i; p += sbuf[wave][k] * W2s[k * 32 + j]; }
    p += __shfl_xor(p, 32, 64);
    float s2 = fmaxf(p + b2s[j], 0.f);
    __syncthreads();
    if (!half) sbuf[wave][j] = s2;
    __syncthreads();

    p = 0.f;
    for (int i = 0; i < 16; ++i) { int k = half * 16 + i; p += sbuf[wave][k] * W3s[k * 32 + j]; }
    p += __shfl_xor(p, 32, 64);
    float s3 = fmaxf(p + b3s[j], 0.f);
    if (!half) S[(size_t)node * 32 + j] = s3;
}

// ---------------- per-graph Gram: out[g][f][e] = sum_n S[g,n,f]*S[g,n,e] ----------------
__global__ __launch_bounds__(256) void gram(const float* __restrict__ S,
                                            float* __restrict__ out) {
    __shared__ float Sg[256 * 32];
    int t = threadIdx.x, g = blockIdx.x;
    const float4* src = (const float4*)(S + (size_t)g * 8192);
    float4* dst = (float4*)Sg;
    for (int i = 0; i < 8; ++i) dst[t + i * 256] = src[t + i * 256];
    __syncthreads();

    int f = t >> 3, e0 = (t & 7) << 2;
    float4 a = {0.f, 0.f, 0.f, 0.f};
    for (int n = 0; n < 256; ++n) {
        float sf = Sg[n * 32 + f];
        float4 se = *(const float4*)&Sg[n * 32 + e0];
        a.x += sf * se.x; a.y += sf * se.y; a.z += sf * se.z; a.w += sf * se.w;
    }
    *(float4*)(out + (size_t)g * 1024 + f * 32 + e0) = a;
}

// ---------------- per-graph MLP: 1024->32->32->2 (fp32) ----------------
__global__ __launch_bounds__(256) void graph_mlp(const float* __restrict__ HH,
                                                 const float* Wm1, const float* bm1,
                                                 const float* Wm2, const float* bm2,
                                                 const float* Wm3, const float* bm3,
                                                 float* __restrict__ out) {
    __shared__ float hh[1024];
    __shared__ float red[256];
    __shared__ float o1[32];
    __shared__ float o2[32];
    int t = threadIdx.x, g = blockIdx.x;
    ((float4*)hh)[t] = ((const float4*)(HH + (size_t)g * 1024))[t];
    __syncthreads();

    int j = t & 31, part = t >> 5;
    float p = 0.f;
    for (int i = 0; i < 128; ++i) { int k = part * 128 + i; p += hh[k] * Wm1[k * 32 + j]; }
    red[t] = p;
    __syncthreads();
    if (t < 32) {
        float s = 0.f;
        for (int q = 0; q < 8; ++q) s += red[q * 32 + t];
        o1[t] = fmaxf(s + bm1[t], 0.f);
    }
    __syncthreads();
    if (t < 32) {
        float s = 0.f;
        for (int k = 0; k < 32; ++k) s += o1[k] * Wm2[k * 32 + t];
        o2[t] = fmaxf(s + bm2[t], 0.f);
    }
    __syncthreads();
    if (t < 2) {
        float s = 0.f;
        for (int k = 0; k < 32; ++k) s += o2[k] * Wm3[k * 2 + t];
        out[524288 + g * 2 + t] = fmaxf(s + bm3[t], 0.f);
    }
}

// ---------------------------------------------------------------------------
extern "C" void kernel_launch(void* const* d_in, const int* in_sizes, int n_in,
                              void* d_out, int out_size, void* d_ws, size_t ws_size,
                              hipStream_t stream) {
    const float* x   = (const float*)d_in[0];
    const int*   ei  = (const int*)d_in[1];
    const float* W1a = (const float*)d_in[2];  const float* b1a = (const float*)d_in[3];
    const float* W2a = (const float*)d_in[4];  const float* b2a = (const float*)d_in[5];
    const float* W1b = (const float*)d_in[6];  const float* b1b = (const float*)d_in[7];
    const float* W2b = (const float*)d_in[8];  const float* b2b = (const float*)d_in[9];
    const float* Ws1 = (const float*)d_in[10]; const float* bs1 = (const float*)d_in[11];
    const float* Ws2 = (const float*)d_in[12]; const float* bs2 = (const float*)d_in[13];
    const float* Ws3 = (const float*)d_in[14]; const float* bs3 = (const float*)d_in[15];
    const float* Wm1 = (const float*)d_in[16]; const float* bm1 = (const float*)d_in[17];
    const float* Wm2 = (const float*)d_in[18]; const float* bm2 = (const float*)d_in[19];
    const float* Wm3 = (const float*)d_in[20]; const float* bm3 = (const float*)d_in[21];
    float* out = (float*)d_out;

    const int* gsrc = ei;
    const int* gdst = ei + NE;

    char* ws = (char*)d_ws;
    size_t off = 0;
    auto alloc = [&](size_t bytes) { size_t r = off; off = (off + bytes + 255) & ~(size_t)255; return r; };
    int*  bcnt   = (int*)(ws + alloc((size_t)NB * 4));
    int*  bbase  = (int*)(ws + alloc((size_t)(NB + 1) * 4));
    int*  cursor = (int*)(ws + alloc((size_t)NB * 4));
    u32*  ebuf   = (u32*)(ws + alloc((size_t)NE * 4));
    u16*  Wt     = (u16*)(ws + alloc(4 * 16384 * 2));
    u16*  X0     = (u16*)(ws + alloc((size_t)NN * 128 * 2));   // xb / hA / hB
    u16*  B1     = (u16*)(ws + alloc((size_t)NN * 128 * 2));
    u16*  B2     = (u16*)(ws + alloc((size_t)NN * 128 * 2));
    float* S     = (float*)B1;                                  // alias: B1 dead after last gemm
    (void)ws_size; (void)n_in; (void)in_sizes; (void)out_size;

    // ---- edge binning ----
    hipMemsetAsync(bcnt, 0, (size_t)NB * 4, stream);
    bin_count<<<NE / BCH, 256, 0, stream>>>(gdst, bcnt);
    scan_buckets<<<1, 1024, 0, stream>>>(bcnt, bbase, cursor);
    bin_scatter<<<NE / BCH, 256, 0, stream>>>(gsrc, gdst, cursor, ebuf);

    // ---- casts ----
    cast_x<<<NN * 128 / (256 * 8), 256, 0, stream>>>(x, X0);
    transpose_w<<<4, 256, 0, stream>>>(W1a, W2a, W1b, W2b, Wt);

    // ---- layer A ----
    aggregate_bucket<<<NB, 512, 0, stream>>>(X0, ebuf, bbase, B1);
    gemm_relu<<<NN / 64, 256, 0, stream>>>(B1, Wt + 0 * 16384, b1a, B2);
    gemm_relu<<<NN / 64, 256, 0, stream>>>(B2, Wt + 1 * 16384, b2a, X0);   // hA
    // ---- layer B ----
    aggregate_bucket<<<NB, 512, 0, stream>>>(X0, ebuf, bbase, B1);
    gemm_relu<<<NN / 64, 256, 0, stream>>>(B1, Wt + 2 * 16384, b1b, B2);
    gemm_relu<<<NN / 64, 256, 0, stream>>>(B2, Wt + 3 * 16384, b2b, X0);   // hB

    // ---- normalize + per-node MLP (S aliases B1) ----
    norm_mlp<<<NN / 4, 256, 0, stream>>>(X0, Ws1, bs1, Ws2, bs2, Ws3, bs3, S);
    // ---- per-graph Gram -> out[0:524288], then graph MLP -> out[524288:] ----
    gram<<<NG, 256, 0, stream>>>(S, out);
    graph_mlp<<<NG, 256, 0, stream>>>(out, Wm1, bm1, Wm2, bm2, Wm3, bm3, out);
}